// Round 4
// baseline (255.166 us; speedup 1.0000x reference)
//
#include <hip/hip_runtime.h>
#include <hip/hip_bf16.h>
#include <math.h>

#define V_N   6890
#define N_PTS 16384
#define D_IN  700
#define D_INP 704      // padded K for GEMM1
#define D_HID 256
#define D_OUT 283
#define NCHUNK 16
#define CHUNK  431     // ceil(6890/16)
#define CAND_CAP 16

// ws layout (float units; all 16B aligned) -- same as R3
#define RINV_OFF 0              // V*9 -> 62016
#define KP4_OFF  62016          // V*4 floats
#define KNN_OFF  89600          // (unused now)
#define PD_OFF   105984         // 16384*16 doubles = 524288 floats
#define PI_OFF   630272         // 16384*16 ints
#define WT1_OFF  892416         // 256*704 bf16
#define WT2_OFF  982528
#define WT3_OFF  1015296
#define X_OFF    1048064        // 16384*704 bf16
#define H1_OFF   6815232        // 16384*256 bf16
#define H2_OFF   8912384
// end ~11.0M floats = ~44 MB

typedef __attribute__((ext_vector_type(8))) short short8;
typedef __attribute__((ext_vector_type(4))) float f32x4;

__device__ __forceinline__ unsigned short f2bf(float f) {
    unsigned int u = __builtin_bit_cast(unsigned int, f);
    u += 0x7fffu + ((u >> 16) & 1u);   // RNE
    return (unsigned short)(u >> 16);
}

__device__ __forceinline__ void glds16(const void* g, void* l) {
    __builtin_amdgcn_global_load_lds(
        (const __attribute__((address_space(1))) void*)g,
        (__attribute__((address_space(3))) void*)l, 16, 0, 0);
}

// ---------------- merged prep (blocks 0..26) + weight convert (blocks 27+) ----------------
#define PREP_BLOCKS 27
__global__ __launch_bounds__(256) void prep_wconv_kernel(
    const float* __restrict__ trans, const float* __restrict__ keyp,
    float* __restrict__ rinv, float4* __restrict__ kp4,
    const float* __restrict__ W1, const float* __restrict__ W2,
    const float* __restrict__ W3, unsigned short* __restrict__ wt1,
    unsigned short* __restrict__ wt2, unsigned short* __restrict__ wt3)
{
    if (blockIdx.x < PREP_BLOCKS) {
        int v = blockIdx.x * 256 + threadIdx.x;
        if (v >= V_N) return;
        float m[16];
#pragma unroll
        for (int i = 0; i < 16; ++i) m[i] = trans[i * V_N + v];

        float i0  =  m[5]*m[10]*m[15] - m[5]*m[11]*m[14] - m[9]*m[6]*m[15] + m[9]*m[7]*m[14] + m[13]*m[6]*m[11] - m[13]*m[7]*m[10];
        float i4  = -m[4]*m[10]*m[15] + m[4]*m[11]*m[14] + m[8]*m[6]*m[15] - m[8]*m[7]*m[14] - m[12]*m[6]*m[11] + m[12]*m[7]*m[10];
        float i8  =  m[4]*m[9]*m[15]  - m[4]*m[11]*m[13] - m[8]*m[5]*m[15] + m[8]*m[7]*m[13] + m[12]*m[5]*m[11] - m[12]*m[7]*m[9];
        float i12 = -m[4]*m[9]*m[14]  + m[4]*m[10]*m[13] + m[8]*m[5]*m[14] - m[8]*m[6]*m[13] - m[12]*m[5]*m[10] + m[12]*m[6]*m[9];
        float i1  = -m[1]*m[10]*m[15] + m[1]*m[11]*m[14] + m[9]*m[2]*m[15] - m[9]*m[3]*m[14] - m[13]*m[2]*m[11] + m[13]*m[3]*m[10];
        float i5  =  m[0]*m[10]*m[15] - m[0]*m[11]*m[14] - m[8]*m[2]*m[15] + m[8]*m[3]*m[14] + m[12]*m[2]*m[11] - m[12]*m[3]*m[10];
        float i9  = -m[0]*m[9]*m[15]  + m[0]*m[11]*m[13] + m[8]*m[1]*m[15] - m[8]*m[3]*m[13] - m[12]*m[1]*m[11] + m[12]*m[3]*m[9];
        float i2  =  m[1]*m[6]*m[15]  - m[1]*m[7]*m[14]  - m[5]*m[2]*m[15] + m[5]*m[3]*m[14] + m[13]*m[2]*m[7]  - m[13]*m[3]*m[6];
        float i6  = -m[0]*m[6]*m[15]  + m[0]*m[7]*m[14]  + m[4]*m[2]*m[15] - m[4]*m[3]*m[14] - m[12]*m[2]*m[7]  + m[12]*m[3]*m[6];
        float i10 =  m[0]*m[5]*m[15]  - m[0]*m[7]*m[13]  - m[4]*m[1]*m[15] + m[4]*m[3]*m[13] + m[12]*m[1]*m[7]  - m[12]*m[3]*m[5];

        float det = m[0]*i0 + m[1]*i4 + m[2]*i8 + m[3]*i12;
        float id = 1.0f / det;
        rinv[v*9+0] = i0*id;  rinv[v*9+1] = i1*id;  rinv[v*9+2] = i2*id;
        rinv[v*9+3] = i4*id;  rinv[v*9+4] = i5*id;  rinv[v*9+5] = i6*id;
        rinv[v*9+6] = i8*id;  rinv[v*9+7] = i9*id;  rinv[v*9+8] = i10*id;

        float kx = keyp[v*3], ky = keyp[v*3+1], kz = keyp[v*3+2];
        kp4[v] = make_float4(kx, ky, kz, kx*kx + ky*ky + kz*kz);
    } else {
        int idx = (blockIdx.x - PREP_BLOCKS) * 256 + threadIdx.x;
        const int N1 = 256 * D_INP;
        const int N2 = 256 * 256;
        if (idx < N1) {
            int n = idx / D_INP, k = idx - n * D_INP;
            float v = (k < D_IN) ? W1[k * 256 + n] : 0.0f;
            wt1[n * D_INP + k] = f2bf(v);
        } else if (idx < N1 + N2) {
            int t = idx - N1;
            int n = t >> 8, k = t & 255;
            wt2[n * 256 + k] = f2bf(W2[k * 256 + n]);
        } else if (idx < N1 + 2 * N2) {
            int t = idx - N1 - N2;
            int n = t >> 8, k = t & 255;
            wt3[n * 256 + k] = f2bf(W3[k * 256 + n]);
        }
    }
}

// ---------------- KNN: fp32 scan w/ LDS candidate collection + fp64 refine ----------------
// Candidate store (LDS side effect) prevents if-conversion of the rare path.
// fp64 refine uses the exact formula of the verified always-fp64 version, so the
// final argmin decision is unchanged.
__global__ __launch_bounds__(256) void knn_part_kernel(
    const float* __restrict__ pts, const float4* __restrict__ kp4,
    double* __restrict__ pd, int* __restrict__ pi)
{
    __shared__ float4 skp[CHUNK];                       // ~6.9 KB, .w = 0.5*|k|^2
    __shared__ unsigned short scand[256 * CAND_CAP];    // 8 KB

    int tid = threadIdx.x;
    int n = blockIdx.x * 256 + tid;
    int c = blockIdx.y;
    int v0 = c * CHUNK;
    int cnt = min(V_N - v0, CHUNK);

    for (int j = tid; j < cnt; j += 256) {
        float4 k = kp4[v0 + j];
        k.w *= 0.5f;
        skp[j] = k;
    }
    __syncthreads();

    float px = pts[n*6+0], py = pts[n*6+1], pz = pts[n*6+2];

    // sample pre-pass: tight init threshold (min over every 16th kp)
    float smin = 1e30f;
    for (int j = 0; j < cnt; j += 16) {
        float4 k = skp[j];
        float d = k.w - (px*k.x + py*k.y + pz*k.z);
        smin = fminf(smin, d);
    }
    const float MARGIN = 1e-4f;   // half-distance scale; fp32 err ~1e-5
    float m0 = smin + MARGIN, m1 = m0, m2 = m0, m3 = m0;

    // main pass: 4 independent chains; collect j if dM <= chain-min_prev
    int nc = 0;
    int j = 0;
    for (; j + 4 <= cnt; j += 4) {
        float4 k0 = skp[j], k1 = skp[j+1], k2 = skp[j+2], k3 = skp[j+3];
        float d0 = k0.w - (px*k0.x + py*k0.y + pz*k0.z);
        float d1 = k1.w - (px*k1.x + py*k1.y + pz*k1.z);
        float d2 = k2.w - (px*k2.x + py*k2.y + pz*k2.z);
        float d3 = k3.w - (px*k3.x + py*k3.y + pz*k3.z);
        if (d0 <= m0) { if (nc < CAND_CAP) scand[tid*CAND_CAP + nc] = (unsigned short)(j);   nc++; }
        if (d1 <= m1) { if (nc < CAND_CAP) scand[tid*CAND_CAP + nc] = (unsigned short)(j+1); nc++; }
        if (d2 <= m2) { if (nc < CAND_CAP) scand[tid*CAND_CAP + nc] = (unsigned short)(j+2); nc++; }
        if (d3 <= m3) { if (nc < CAND_CAP) scand[tid*CAND_CAP + nc] = (unsigned short)(j+3); nc++; }
        m0 = fminf(m0, d0 + MARGIN);
        m1 = fminf(m1, d1 + MARGIN);
        m2 = fminf(m2, d2 + MARGIN);
        m3 = fminf(m3, d3 + MARGIN);
    }
    for (; j < cnt; ++j) {
        float4 k0 = skp[j];
        float d0 = k0.w - (px*k0.x + py*k0.y + pz*k0.z);
        if (d0 <= m0) { if (nc < CAND_CAP) scand[tid*CAND_CAP + nc] = (unsigned short)j; nc++; }
        m0 = fminf(m0, d0 + MARGIN);
    }

    // fp64 refine (formula bit-identical to the verified fp64 version)
    double pxd = (double)px, pyd = (double)py, pzd = (double)pz;
    double ppd = pxd*pxd + pyd*pyd + pzd*pzd;
    double best = 1e300; int bi = 0x7fffffff;
    if (nc <= CAND_CAP) {
        for (int q = 0; q < nc; ++q) {
            int jj = scand[tid*CAND_CAP + q];
            float4 k = skp[jj];
            double kx = (double)k.x, ky = (double)k.y, kz = (double)k.z;
            double d = ppd - 2.0*(pxd*kx + pyd*ky + pzd*kz) + (kx*kx + ky*ky + kz*kz);
            if (d < best) { best = d; bi = v0 + jj; }   // jj increasing -> first-min tiebreak
        }
    } else {
        // overflow fallback (effectively never taken): exact full scan
        for (int jj = 0; jj < cnt; ++jj) {
            float4 k = skp[jj];
            double kx = (double)k.x, ky = (double)k.y, kz = (double)k.z;
            double d = ppd - 2.0*(pxd*kx + pyd*ky + pzd*kz) + (kx*kx + ky*ky + kz*kz);
            if (d < best) { best = d; bi = v0 + jj; }
        }
    }
    pd[(size_t)n*NCHUNK + c] = best;
    pi[(size_t)n*NCHUNK + c] = bi;
}

// ---------------- features: inline KNN reduce + X row (bf16) + posenc tail ----------------
__global__ __launch_bounds__(256) void feat_kernel(
    const float* __restrict__ pts, const float* __restrict__ keyp,
    const int* __restrict__ neigh, const float* __restrict__ restp,
    const float* __restrict__ latent, const float* __restrict__ rinv,
    const double* __restrict__ pd, const int* __restrict__ pi,
    unsigned short* __restrict__ X, float* __restrict__ out)
{
    int w = threadIdx.x >> 6;       // wave in block
    int lane = threadIdx.x & 63;
    int n = blockIdx.x * 4 + w;     // point id

    __shared__ float s_vf[4][28];
    __shared__ int   s_vi[4][8];
    __shared__ float s_dir[4][4];

    // inline cross-chunk argmin reduce (lexicographic), lanes 0..15
    double rd = 1e300; int ri = 0x7fffffff;
    if (lane < NCHUNK) {
        rd = pd[(size_t)n*NCHUNK + lane];
        ri = pi[(size_t)n*NCHUNK + lane];
    }
#pragma unroll
    for (int off = 8; off >= 1; off >>= 1) {
        double od = __shfl_xor(rd, off);
        int    oi = __shfl_xor(ri, off);
        if (od < rd || (od == rd && oi < ri)) { rd = od; ri = oi; }
    }
    int k = __shfl(ri, 0);

    float px = pts[n*6+0], py = pts[n*6+1], pz = pts[n*6+2];

    if (lane < 7) {
        int v = neigh[k*7 + lane];
        s_vi[w][lane] = v;
        float dx = px - keyp[v*3+0];
        float dy = py - keyp[v*3+1];
        float dz = pz - keyp[v*3+2];
        s_vf[w][21 + lane] = sqrtf(dx*dx + dy*dy + dz*dz);
    }
    if (lane == 7) {
        float dx = px - keyp[k*3+0];
        float dy = py - keyp[k*3+1];
        float dz = pz - keyp[k*3+2];
        const float* R = &rinv[k*9];
        float d0 = R[0]*dx + R[1]*dy + R[2]*dz;
        float d1 = R[3]*dx + R[4]*dy + R[5]*dz;
        float d2 = R[6]*dx + R[7]*dy + R[8]*dz;
        float nrm = fmaxf(sqrtf(d0*d0 + d1*d1 + d2*d2), 1e-12f);
        s_dir[w][0] = d0/nrm; s_dir[w][1] = d1/nrm; s_dir[w][2] = d2/nrm;
    }
    __syncthreads();
    if (lane < 21) {
        s_vf[w][lane] = restp[s_vi[w][lane/3]*3 + (lane%3)];
    }
    __syncthreads();

    // output tail (fp32): [dir(3), sin f-major (12), cos (12)]
    if (lane < 27) {
        float val;
        if (lane < 3) val = s_dir[w][lane];
        else if (lane < 15) { int t = lane - 3;  val = sinf(s_dir[w][t%3] * (float)(1 << (t/3))); }
        else                { int t = lane - 15; val = cosf(s_dir[w][t%3] * (float)(1 << (t/3))); }
        out[(size_t)n*D_OUT + 256 + lane] = val;
    }

    // X row bf16: [vfeat(28), sin (280), cos (280), lfeat(112), pad(4)=0]
    for (int i = lane; i < D_INP; i += 64) {
        float val;
        if (i < 28) {
            val = s_vf[w][i];
        } else if (i < 308) {
            int t = i - 28;  val = sinf(s_vf[w][t%28] * (float)(1 << (t/28)));
        } else if (i < 588) {
            int t = i - 308; val = cosf(s_vf[w][t%28] * (float)(1 << (t/28)));
        } else if (i < 700) {
            int t = i - 588; val = latent[s_vi[w][t >> 4]*16 + (t & 15)];
        } else {
            val = 0.0f;
        }
        X[(size_t)n*D_INP + i] = f2bf(val);
    }
}

// ---------------- bf16 MFMA GEMM: C = [relu](A @ Wt^T + b) ----------------
__global__ __launch_bounds__(512) void mfma_gemm(
    const unsigned short* __restrict__ A, int lda,
    const unsigned short* __restrict__ Wt, int ldw,
    const float* __restrict__ bias,
    void* __restrict__ Cout, int ldc, int K, int relu_bf16out)
{
    __shared__ unsigned short As[128 * 32];   // [m][k], 8KB
    __shared__ unsigned short Bs[128 * 32];   // [n][k], 8KB

    int t = threadIdx.x;
    int bm = blockIdx.x * 128;
    int bn = blockIdx.y * 128;

    int l = t & 63, w = t >> 6;
    int mbase = (w >> 2) * 64;
    int nbase = (w & 3) * 32;
    int lrow = l & 15;
    int lk = (l >> 4) * 8;

    const char* gA0 = (const char*)(A + (size_t)(bm + (t >> 2)) * lda) + (t & 3) * 16;
    const char* gB0 = (const char*)(Wt + (size_t)(bn + (t >> 2)) * ldw) + (t & 3) * 16;
    char* lA = (char*)As + t * 16;
    char* lB = (char*)Bs + t * 16;

    f32x4 acc[4][2];
#pragma unroll
    for (int i = 0; i < 4; ++i)
#pragma unroll
        for (int j = 0; j < 2; ++j) acc[i][j] = {0.f, 0.f, 0.f, 0.f};

    for (int k0 = 0; k0 < K; k0 += 32) {
        glds16(gA0 + (size_t)k0 * 2, lA);
        glds16(gB0 + (size_t)k0 * 2, lB);
        __syncthreads();

        short8 af[4], bf[2];
#pragma unroll
        for (int mi = 0; mi < 4; ++mi)
            af[mi] = *(const short8*)&As[(mbase + mi * 16 + lrow) * 32 + lk];
#pragma unroll
        for (int ni = 0; ni < 2; ++ni)
            bf[ni] = *(const short8*)&Bs[(nbase + ni * 16 + lrow) * 32 + lk];

#pragma unroll
        for (int mi = 0; mi < 4; ++mi)
#pragma unroll
            for (int ni = 0; ni < 2; ++ni)
                acc[mi][ni] = __builtin_amdgcn_mfma_f32_16x16x32_bf16(
                    af[mi], bf[ni], acc[mi][ni], 0, 0, 0);
        __syncthreads();
    }

    // epilogue: C/D layout col=lane&15, row=(lane>>4)*4+reg
#pragma unroll
    for (int mi = 0; mi < 4; ++mi) {
#pragma unroll
        for (int ni = 0; ni < 2; ++ni) {
            int col = bn + nbase + ni * 16 + (l & 15);
            float bv = bias[col];
#pragma unroll
            for (int r = 0; r < 4; ++r) {
                int row = bm + mbase + mi * 16 + (l >> 4) * 4 + r;
                float val = acc[mi][ni][r] + bv;
                if (relu_bf16out) {
                    val = fmaxf(val, 0.0f);
                    ((unsigned short*)Cout)[(size_t)row * ldc + col] = f2bf(val);
                } else {
                    ((float*)Cout)[(size_t)row * ldc + col] = val;
                }
            }
        }
    }
}

extern "C" void kernel_launch(void* const* d_in, const int* in_sizes, int n_in,
                              void* d_out, int out_size, void* d_ws, size_t ws_size,
                              hipStream_t stream) {
    const float* pts    = (const float*)d_in[0];
    const float* keyp   = (const float*)d_in[1];
    const float* trans  = (const float*)d_in[2];
    const int*   neigh  = (const int*)d_in[3];
    const float* restp  = (const float*)d_in[4];
    const float* latent = (const float*)d_in[5];
    const float* W1     = (const float*)d_in[6];
    const float* b1     = (const float*)d_in[7];
    const float* W2     = (const float*)d_in[8];
    const float* b2     = (const float*)d_in[9];
    const float* W3     = (const float*)d_in[10];
    const float* b3     = (const float*)d_in[11];
    float* out = (float*)d_out;

    float* wsf = (float*)d_ws;
    float*          rinv = wsf + RINV_OFF;
    float4*         kp4  = (float4*)(wsf + KP4_OFF);
    double*         pd   = (double*)(wsf + PD_OFF);
    int*            pi   = (int*)(wsf + PI_OFF);
    unsigned short* wt1  = (unsigned short*)(wsf + WT1_OFF);
    unsigned short* wt2  = (unsigned short*)(wsf + WT2_OFF);
    unsigned short* wt3  = (unsigned short*)(wsf + WT3_OFF);
    unsigned short* X    = (unsigned short*)(wsf + X_OFF);
    unsigned short* H1   = (unsigned short*)(wsf + H1_OFF);
    unsigned short* H2   = (unsigned short*)(wsf + H2_OFF);

    int wconv_blocks = (256*D_INP + 2*256*256 + 255) / 256;
    prep_wconv_kernel<<<PREP_BLOCKS + wconv_blocks, 256, 0, stream>>>(
        trans, keyp, rinv, kp4, W1, W2, W3, wt1, wt2, wt3);
    knn_part_kernel<<<dim3(N_PTS/256, NCHUNK), 256, 0, stream>>>(pts, kp4, pd, pi);
    feat_kernel<<<N_PTS/4, 256, 0, stream>>>(pts, keyp, neigh, restp, latent, rinv,
                                             pd, pi, X, out);

    mfma_gemm<<<dim3(N_PTS/128, 2), 512, 0, stream>>>(X,  D_INP, wt1, D_INP, b1, H1,  256, D_INP, 1);
    mfma_gemm<<<dim3(N_PTS/128, 2), 512, 0, stream>>>(H1, D_HID, wt2, D_HID, b2, H2,  256, D_HID, 1);
    mfma_gemm<<<dim3(N_PTS/128, 2), 512, 0, stream>>>(H2, D_HID, wt3, D_HID, b3, out, D_OUT, D_HID, 0);
}